// Round 1
// baseline (424.443 us; speedup 1.0000x reference)
//
#include <hip/hip_runtime.h>

typedef unsigned short u16;
typedef unsigned int u32;
typedef float f32x4 __attribute__((ext_vector_type(4)));
typedef __bf16 bf16x8 __attribute__((ext_vector_type(8)));

__device__ __forceinline__ u16 f2bf(float f) {
  u32 u = __builtin_bit_cast(u32, f);
  u32 r = (u + 0x7fffu + ((u >> 16) & 1u)) >> 16;
  return (u16)r;
}

// ---------------- fp32 -> bf16 conversion (x, Wq|Wkv concat, Wo) ----------------
// segments (float4 units): x 1048576 | Wq 262144 | Wkv 131072 | Wo 262144 = 1703936 total
__global__ __launch_bounds__(256) void cvt_kernel(
    const float4* __restrict__ x, const float4* __restrict__ wq,
    const float4* __restrict__ wkv, const float4* __restrict__ wo,
    uint2* __restrict__ xb, uint2* __restrict__ wqkvb, uint2* __restrict__ wob) {
  long i = (long)blockIdx.x * 256 + threadIdx.x;
  const float4* src; uint2* dst; long off;
  if (i < 1048576)      { src = x;   dst = xb;             off = i; }
  else if (i < 1310720) { src = wq;  dst = wqkvb;          off = i - 1048576; }
  else if (i < 1441792) { src = wkv; dst = wqkvb + 262144; off = i - 1310720; }
  else                  { src = wo;  dst = wob;            off = i - 1441792; }
  float4 v = src[off];
  uint2 o;
  o.x = ((u32)f2bf(v.y) << 16) | (u32)f2bf(v.x);
  o.y = ((u32)f2bf(v.w) << 16) | (u32)f2bf(v.z);
  dst[off] = o;
}

// ---------------- shared 128x128 bf16 GEMM core (C = A * W^T) ----------------
// A: M x K row-major bf16(u16), W: N x K row-major bf16(u16)
// 256 threads = 4 waves (2x2), each wave 64x64 = 4x4 frags of 16x16x32 MFMA
__device__ __forceinline__ void gemm_core(
    const u16* __restrict__ A, const u16* __restrict__ W, int K,
    f32x4 acc[4][4], u16 As[128][40], u16 Ws[128][40]) {
  const int t = threadIdx.x;
  const int lane = t & 63;
  const int w = t >> 6;
  const int wm = (w >> 1) * 64, wn = (w & 1) * 64;
  const long bm = (long)blockIdx.x * 128, bn = (long)blockIdx.y * 128;
  const int sr = t >> 2;          // staging row 0..63
  const int sc = (t & 3) * 8;     // staging col 0,8,16,24
  const int cc = lane & 15;       // frag row/col within 16
  const int kg8 = (lane >> 4) * 8;

#pragma unroll
  for (int i = 0; i < 4; i++)
#pragma unroll
    for (int j = 0; j < 4; j++) acc[i][j] = f32x4{0.f, 0.f, 0.f, 0.f};

  for (int k0 = 0; k0 < K; k0 += 32) {
    *(uint4*)&As[sr][sc]      = *(const uint4*)&A[(bm + sr) * K + k0 + sc];
    *(uint4*)&As[sr + 64][sc] = *(const uint4*)&A[(bm + sr + 64) * K + k0 + sc];
    *(uint4*)&Ws[sr][sc]      = *(const uint4*)&W[(bn + sr) * K + k0 + sc];
    *(uint4*)&Ws[sr + 64][sc] = *(const uint4*)&W[(bn + sr + 64) * K + k0 + sc];
    __syncthreads();
    bf16x8 af[4], wf[4];
#pragma unroll
    for (int i = 0; i < 4; i++) af[i] = *(const bf16x8*)&As[wm + i * 16 + cc][kg8];
#pragma unroll
    for (int j = 0; j < 4; j++) wf[j] = *(const bf16x8*)&Ws[wn + j * 16 + cc][kg8];
#pragma unroll
    for (int i = 0; i < 4; i++)
#pragma unroll
      for (int j = 0; j < 4; j++)
        acc[i][j] = __builtin_amdgcn_mfma_f32_16x16x32_bf16(af[i], wf[j], acc[i][j], 0, 0, 0);
    __syncthreads();
  }
}

// ---------------- GEMM1: qkv projection + routing epilogue ----------------
// cols 0..1023 -> Q (scaled by 0.125), cols 1024..1535 -> K / V^T per group
__global__ __launch_bounds__(256) void gemm_qkv_kernel(
    const u16* __restrict__ A, const u16* __restrict__ W,
    u16* __restrict__ Qb, u16* __restrict__ Kb, u16* __restrict__ VTb) {
  __shared__ __align__(16) u16 As[128][40];
  __shared__ __align__(16) u16 Ws[128][40];
  f32x4 acc[4][4];
  gemm_core(A, W, 1024, acc, As, Ws);
  const int t = threadIdx.x, lane = t & 63, w = t >> 6;
  const int wm = (w >> 1) * 64, wn = (w & 1) * 64;
  const int bm = blockIdx.x * 128, bn = blockIdx.y * 128;
  const int rr = (lane >> 4) * 4, cc = lane & 15;
#pragma unroll
  for (int i = 0; i < 4; i++)
#pragma unroll
    for (int jf = 0; jf < 4; jf++)
#pragma unroll
      for (int j = 0; j < 4; j++) {
        int m = bm + wm + i * 16 + rr + j;
        int n = bn + wn + jf * 16 + cc;
        float v = acc[i][jf][j];
        if (n < 1024) {
          Qb[(long)m * 1024 + n] = f2bf(v * 0.125f);   // fold SCALE into Q
        } else {
          int c = n - 1024, g = c >> 7, rm = c & 127;
          int b = m >> 11, pos = m & 2047;
          long base = (long)(b * 4 + g);
          if (rm < 64) Kb[(base * 2048 + pos) * 64 + rm] = f2bf(v);
          else         VTb[(base * 64 + (rm - 64)) * 2048 + pos] = f2bf(v);
        }
      }
}

// ---------------- GEMM2: output projection, fp32 out ----------------
__global__ __launch_bounds__(256) void gemm_out_kernel(
    const u16* __restrict__ A, const u16* __restrict__ W, float* __restrict__ out) {
  __shared__ __align__(16) u16 As[128][40];
  __shared__ __align__(16) u16 Ws[128][40];
  f32x4 acc[4][4];
  gemm_core(A, W, 1024, acc, As, Ws);
  const int t = threadIdx.x, lane = t & 63, w = t >> 6;
  const int wm = (w >> 1) * 64, wn = (w & 1) * 64;
  const int bm = blockIdx.x * 128, bn = blockIdx.y * 128;
  const int rr = (lane >> 4) * 4, cc = lane & 15;
#pragma unroll
  for (int i = 0; i < 4; i++)
#pragma unroll
    for (int jf = 0; jf < 4; jf++)
#pragma unroll
      for (int j = 0; j < 4; j++) {
        int m = bm + wm + i * 16 + rr + j;
        int n = bn + wn + jf * 16 + cc;
        out[(long)m * 1024 + n] = acc[i][jf][j];
      }
}

// ---------------- flash attention (causal + ALiBi, GQA) ----------------
// grid: (qtile 0..31, head 0..15, batch 0..1), 256 threads = 4 waves
// wave w owns Q rows qt*64 + w*16 .. +16; iterate 64-key blocks jb=0..qt
__global__ __launch_bounds__(256) void attn_kernel(
    const u16* __restrict__ Q, const u16* __restrict__ Kb,
    const u16* __restrict__ VTb, u16* __restrict__ AT) {
  __shared__ __align__(16) u16 Pl[4][16][72];  // per-wave P tile, padded stride 144B
  const int t = threadIdx.x, lane = t & 63, w = t >> 6;
  const int qt = blockIdx.x, h = blockIdx.y, b = blockIdx.z;
  const int g = h >> 2;
  const int cc = lane & 15, rr = (lane >> 4) * 4, kg8 = (lane >> 4) * 8;
  const int qrow0 = qt * 64 + w * 16;

  // Q fragments (already scaled by 0.125)
  const u16* Qbase = Q + ((long)(b * 2048 + qrow0 + cc)) * 1024 + h * 64;
  bf16x8 qf0 = *(const bf16x8*)(Qbase + kg8);
  bf16x8 qf1 = *(const bf16x8*)(Qbase + 32 + kg8);

  const u16* Kg = Kb  + ((long)(b * 4 + g)) * 2048 * 64;
  const u16* Vg = VTb + ((long)(b * 4 + g)) * 64 * 2048;

  float mrow[4], lsum[4];
  f32x4 acc_o[4];
#pragma unroll
  for (int j = 0; j < 4; j++) { mrow[j] = -1e30f; lsum[j] = 0.f; }
#pragma unroll
  for (int dg = 0; dg < 4; dg++) acc_o[dg] = f32x4{0.f, 0.f, 0.f, 0.f};

  const float slope = exp2f(-0.5f * (float)(h + 1));

  for (int jb = 0; jb <= qt; ++jb) {
    const int kbase = jb * 64;
    // ---- S = Q K^T (16 rows x 64 keys per wave) ----
    f32x4 s[4];
#pragma unroll
    for (int kg = 0; kg < 4; kg++) {
      s[kg] = f32x4{0.f, 0.f, 0.f, 0.f};
      const u16* Kp = Kg + (long)(kbase + kg * 16 + cc) * 64 + kg8;
      bf16x8 k0 = *(const bf16x8*)Kp;
      bf16x8 k1 = *(const bf16x8*)(Kp + 32);
      s[kg] = __builtin_amdgcn_mfma_f32_16x16x32_bf16(qf0, k0, s[kg], 0, 0, 0);
      s[kg] = __builtin_amdgcn_mfma_f32_16x16x32_bf16(qf1, k1, s[kg], 0, 0, 0);
    }
    // ---- ALiBi + causal mask ----
#pragma unroll
    for (int kg = 0; kg < 4; kg++)
#pragma unroll
      for (int j = 0; j < 4; j++) {
        int key = kbase + kg * 16 + cc;
        int qr  = qrow0 + rr + j;
        float sv = s[kg][j] + slope * (float)(key - qr);
        s[kg][j] = (key <= qr) ? sv : -1e30f;
      }
    // ---- online softmax stats (row spread over 16 lanes in group) ----
    float al[4], rs[4];
#pragma unroll
    for (int j = 0; j < 4; j++) {
      float v = fmaxf(fmaxf(s[0][j], s[1][j]), fmaxf(s[2][j], s[3][j]));
      v = fmaxf(v, __shfl_xor(v, 1));
      v = fmaxf(v, __shfl_xor(v, 2));
      v = fmaxf(v, __shfl_xor(v, 4));
      v = fmaxf(v, __shfl_xor(v, 8));
      float nm = fmaxf(mrow[j], v);
      al[j] = __expf(mrow[j] - nm);
      mrow[j] = nm;
      rs[j] = 0.f;
    }
#pragma unroll
    for (int kg = 0; kg < 4; kg++)
#pragma unroll
      for (int j = 0; j < 4; j++) {
        float p = __expf(s[kg][j] - mrow[j]);
        s[kg][j] = p;
        rs[j] += p;
      }
#pragma unroll
    for (int j = 0; j < 4; j++) {
      rs[j] += __shfl_xor(rs[j], 1);
      rs[j] += __shfl_xor(rs[j], 2);
      rs[j] += __shfl_xor(rs[j], 4);
      rs[j] += __shfl_xor(rs[j], 8);
      lsum[j] = lsum[j] * al[j] + rs[j];
    }
#pragma unroll
    for (int dg = 0; dg < 4; dg++)
#pragma unroll
      for (int j = 0; j < 4; j++) acc_o[dg][j] *= al[j];

    // ---- P: C-layout -> A-layout via per-wave LDS round trip ----
    __syncthreads();
#pragma unroll
    for (int kg = 0; kg < 4; kg++)
#pragma unroll
      for (int j = 0; j < 4; j++)
        Pl[w][rr + j][kg * 16 + cc] = f2bf(s[kg][j]);
    __syncthreads();
    bf16x8 pa0 = *(const bf16x8*)&Pl[w][cc][kg8];
    bf16x8 pa1 = *(const bf16x8*)&Pl[w][cc][32 + kg8];

    // ---- O += P V  (V^T fragments contiguous from global) ----
#pragma unroll
    for (int kf = 0; kf < 2; kf++) {
      bf16x8 pf = (kf == 0) ? pa0 : pa1;
#pragma unroll
      for (int dg = 0; dg < 4; dg++) {
        bf16x8 vf = *(const bf16x8*)&Vg[(long)(dg * 16 + cc) * 2048 + kbase + kf * 32 + kg8];
        acc_o[dg] = __builtin_amdgcn_mfma_f32_16x16x32_bf16(pf, vf, acc_o[dg], 0, 0, 0);
      }
    }
  }

  // ---- normalize + write attn output (b, pos, h*64+d) bf16 ----
#pragma unroll
  for (int dg = 0; dg < 4; dg++)
#pragma unroll
    for (int j = 0; j < 4; j++) {
      int qr = qrow0 + rr + j;
      AT[((long)(b * 2048 + qr)) * 1024 + h * 64 + dg * 16 + cc] =
          f2bf(acc_o[dg][j] / lsum[j]);
    }
}

// ---------------- launcher ----------------
extern "C" void kernel_launch(void* const* d_in, const int* in_sizes, int n_in,
                              void* d_out, int out_size, void* d_ws, size_t ws_size,
                              hipStream_t stream) {
  const float* x   = (const float*)d_in[0];
  const float* Wq  = (const float*)d_in[1];
  const float* Wkv = (const float*)d_in[2];
  const float* Wo  = (const float*)d_in[3];
  float* out = (float*)d_out;
  char* ws = (char*)d_ws;

  // ws layout (bytes)
  u16* xb    = (u16*)(ws);              //  8,388,608  x bf16 (4096x1024)
  u16* wqkvb = (u16*)(ws + 8388608);    //  3,145,728  Wq|Wkv bf16 (1536x1024)
  u16* wob   = (u16*)(ws + 11534336);   //  2,097,152  Wo bf16 (1024x1024)
  u16* Qb    = (u16*)(ws + 13631488);   //  8,388,608  Q bf16, pre-scaled
  u16* Kb    = (u16*)(ws + 22020096);   //  2,097,152  K[b][g][pos][64]
  u16* VTb   = (u16*)(ws + 24117248);   //  2,097,152  V^T[b][g][64][pos]
  u16* AT    = (u16*)(ws + 26214400);   //  8,388,608  attn out bf16 (4096x1024)

  cvt_kernel<<<6656, 256, 0, stream>>>(
      (const float4*)x, (const float4*)Wq, (const float4*)Wkv, (const float4*)Wo,
      (uint2*)xb, (uint2*)wqkvb, (uint2*)wob);

  gemm_qkv_kernel<<<dim3(32, 12), 256, 0, stream>>>(xb, wqkvb, Qb, Kb, VTb);

  attn_kernel<<<dim3(32, 16, 2), 256, 0, stream>>>(Qb, Kb, VTb, AT);

  gemm_out_kernel<<<dim3(32, 8), 256, 0, stream>>>(AT, wob, out);
}

// Round 2
// 293.324 us; speedup vs baseline: 1.4470x; 1.4470x over previous
//
#include <hip/hip_runtime.h>

typedef unsigned short u16;
typedef unsigned int u32;
typedef float f32x4 __attribute__((ext_vector_type(4)));
typedef __bf16 bf16x8 __attribute__((ext_vector_type(8)));

__device__ __forceinline__ u16 f2bf(float f) {
  u32 u = __builtin_bit_cast(u32, f);
  u32 r = (u + 0x7fffu + ((u >> 16) & 1u)) >> 16;
  return (u16)r;
}

// ---------------- fp32 -> bf16 conversion (x, Wq|Wkv concat, Wo) ----------------
__global__ __launch_bounds__(256) void cvt_kernel(
    const float4* __restrict__ x, const float4* __restrict__ wq,
    const float4* __restrict__ wkv, const float4* __restrict__ wo,
    uint2* __restrict__ xb, uint2* __restrict__ wqkvb, uint2* __restrict__ wob) {
  long i = (long)blockIdx.x * 256 + threadIdx.x;
  const float4* src; uint2* dst; long off;
  if (i < 1048576)      { src = x;   dst = xb;             off = i; }
  else if (i < 1310720) { src = wq;  dst = wqkvb;          off = i - 1048576; }
  else if (i < 1441792) { src = wkv; dst = wqkvb + 262144; off = i - 1310720; }
  else                  { src = wo;  dst = wob;            off = i - 1441792; }
  float4 v = src[off];
  uint2 o;
  o.x = ((u32)f2bf(v.y) << 16) | (u32)f2bf(v.x);
  o.y = ((u32)f2bf(v.w) << 16) | (u32)f2bf(v.z);
  dst[off] = o;
}

// ---------------- shared 128x128 bf16 GEMM core (C = A * W^T) ----------------
__device__ __forceinline__ void gemm_core(
    const u16* __restrict__ A, const u16* __restrict__ W, int K,
    f32x4 acc[4][4], u16 As[128][40], u16 Ws[128][40]) {
  const int t = threadIdx.x;
  const int lane = t & 63;
  const int w = t >> 6;
  const int wm = (w >> 1) * 64, wn = (w & 1) * 64;
  const long bm = (long)blockIdx.x * 128, bn = (long)blockIdx.y * 128;
  const int sr = t >> 2;
  const int sc = (t & 3) * 8;
  const int cc = lane & 15;
  const int kg8 = (lane >> 4) * 8;

#pragma unroll
  for (int i = 0; i < 4; i++)
#pragma unroll
    for (int j = 0; j < 4; j++) acc[i][j] = f32x4{0.f, 0.f, 0.f, 0.f};

  for (int k0 = 0; k0 < K; k0 += 32) {
    *(uint4*)&As[sr][sc]      = *(const uint4*)&A[(bm + sr) * K + k0 + sc];
    *(uint4*)&As[sr + 64][sc] = *(const uint4*)&A[(bm + sr + 64) * K + k0 + sc];
    *(uint4*)&Ws[sr][sc]      = *(const uint4*)&W[(bn + sr) * K + k0 + sc];
    *(uint4*)&Ws[sr + 64][sc] = *(const uint4*)&W[(bn + sr + 64) * K + k0 + sc];
    __syncthreads();
    bf16x8 af[4], wf[4];
#pragma unroll
    for (int i = 0; i < 4; i++) af[i] = *(const bf16x8*)&As[wm + i * 16 + cc][kg8];
#pragma unroll
    for (int j = 0; j < 4; j++) wf[j] = *(const bf16x8*)&Ws[wn + j * 16 + cc][kg8];
#pragma unroll
    for (int i = 0; i < 4; i++)
#pragma unroll
      for (int j = 0; j < 4; j++)
        acc[i][j] = __builtin_amdgcn_mfma_f32_16x16x32_bf16(af[i], wf[j], acc[i][j], 0, 0, 0);
    __syncthreads();
  }
}

// ---------------- GEMM1: qkv projection + routing epilogue ----------------
__global__ __launch_bounds__(256) void gemm_qkv_kernel(
    const u16* __restrict__ A, const u16* __restrict__ W,
    u16* __restrict__ Qb, u16* __restrict__ Kb, u16* __restrict__ VTb) {
  __shared__ __align__(16) u16 As[128][40];
  __shared__ __align__(16) u16 Ws[128][40];
  f32x4 acc[4][4];
  gemm_core(A, W, 1024, acc, As, Ws);
  const int t = threadIdx.x, lane = t & 63, w = t >> 6;
  const int wm = (w >> 1) * 64, wn = (w & 1) * 64;
  const int bm = blockIdx.x * 128, bn = blockIdx.y * 128;
  const int rr = (lane >> 4) * 4, cc = lane & 15;
#pragma unroll
  for (int i = 0; i < 4; i++)
#pragma unroll
    for (int jf = 0; jf < 4; jf++)
#pragma unroll
      for (int j = 0; j < 4; j++) {
        int m = bm + wm + i * 16 + rr + j;
        int n = bn + wn + jf * 16 + cc;
        float v = acc[i][jf][j];
        if (n < 1024) {
          Qb[(long)m * 1024 + n] = f2bf(v * 0.125f);
        } else {
          int c = n - 1024, g = c >> 7, rm = c & 127;
          int b = m >> 11, pos = m & 2047;
          long base = (long)(b * 4 + g);
          if (rm < 64) Kb[(base * 2048 + pos) * 64 + rm] = f2bf(v);
          else         VTb[(base * 64 + (rm - 64)) * 2048 + pos] = f2bf(v);
        }
      }
}

// ---------------- GEMM2: output projection, fp32 out ----------------
__global__ __launch_bounds__(256) void gemm_out_kernel(
    const u16* __restrict__ A, const u16* __restrict__ W, float* __restrict__ out) {
  __shared__ __align__(16) u16 As[128][40];
  __shared__ __align__(16) u16 Ws[128][40];
  f32x4 acc[4][4];
  gemm_core(A, W, 1024, acc, As, Ws);
  const int t = threadIdx.x, lane = t & 63, w = t >> 6;
  const int wm = (w >> 1) * 64, wn = (w & 1) * 64;
  const int bm = blockIdx.x * 128, bn = blockIdx.y * 128;
  const int rr = (lane >> 4) * 4, cc = lane & 15;
#pragma unroll
  for (int i = 0; i < 4; i++)
#pragma unroll
    for (int jf = 0; jf < 4; jf++)
#pragma unroll
      for (int j = 0; j < 4; j++) {
        int m = bm + wm + i * 16 + rr + j;
        int n = bn + wn + jf * 16 + cc;
        out[(long)m * 1024 + n] = acc[i][jf][j];
      }
}

// ---------------- flash attention (causal + ALiBi, GQA) ----------------
// grid: (qtile16 0..127, head 0..15, batch 0..1), 256 threads = 4 waves.
// All 4 waves share the SAME 16 Q rows; keys split round-robin across waves
// (jb = w, w+4, ...), private online-softmax state, LDS combine at the end.
// No barriers in the main loop (P remap LDS is wave-private).
__global__ __launch_bounds__(256) void attn_kernel(
    const u16* __restrict__ Q, const u16* __restrict__ Kb,
    const u16* __restrict__ VTb, u16* __restrict__ AT) {
  // union: Pl (main loop, 9216B) / Ol+ml (combine, 17920B)
  __shared__ __align__(16) char lds_raw[17920];
  u16   (*Pl)[16][72] = (u16   (*)[16][72])lds_raw;
  float (*Ol)[16][68] = (float (*)[16][68])lds_raw;
  float (*ml)[2][16]  = (float (*)[2][16])(lds_raw + 17408);

  const int t = threadIdx.x, lane = t & 63, w = t >> 6;
  const int qt = 127 - (int)blockIdx.x;   // LPT: longest blocks dispatch first
  const int h = blockIdx.y, b = blockIdx.z;
  const int g = h >> 2;
  const int cc = lane & 15, rr = (lane >> 4) * 4, kg8 = (lane >> 4) * 8;
  const int qrow0 = qt * 16;
  const int kblocks = (qrow0 + 79) >> 6;  // 64-key blocks covering keys 0..qrow0+15

  const u16* Qbase = Q + ((long)(b * 2048 + qrow0 + cc)) * 1024 + h * 64;
  bf16x8 qf0 = *(const bf16x8*)(Qbase + kg8);
  bf16x8 qf1 = *(const bf16x8*)(Qbase + 32 + kg8);

  const u16* Kg = Kb  + ((long)(b * 4 + g)) * 2048 * 64;
  const u16* Vg = VTb + ((long)(b * 4 + g)) * 64 * 2048;

  float mrow[4], lsum[4];
  f32x4 acc_o[4];
#pragma unroll
  for (int j = 0; j < 4; j++) { mrow[j] = -1e30f; lsum[j] = 0.f; }
#pragma unroll
  for (int dg = 0; dg < 4; dg++) acc_o[dg] = f32x4{0.f, 0.f, 0.f, 0.f};

  const float slope = exp2f(-0.5f * (float)(h + 1));

  for (int jb = w; jb < kblocks; jb += 4) {
    const int kbase = jb * 64;
    // ---- S = Q K^T (16 rows x 64 keys) ----
    f32x4 s[4];
#pragma unroll
    for (int kg = 0; kg < 4; kg++) {
      s[kg] = f32x4{0.f, 0.f, 0.f, 0.f};
      const u16* Kp = Kg + (long)(kbase + kg * 16 + cc) * 64 + kg8;
      bf16x8 k0 = *(const bf16x8*)Kp;
      bf16x8 k1 = *(const bf16x8*)(Kp + 32);
      s[kg] = __builtin_amdgcn_mfma_f32_16x16x32_bf16(qf0, k0, s[kg], 0, 0, 0);
      s[kg] = __builtin_amdgcn_mfma_f32_16x16x32_bf16(qf1, k1, s[kg], 0, 0, 0);
    }
    // ---- ALiBi + causal mask ----
#pragma unroll
    for (int kg = 0; kg < 4; kg++)
#pragma unroll
      for (int j = 0; j < 4; j++) {
        int key = kbase + kg * 16 + cc;
        int qr  = qrow0 + rr + j;
        float sv = s[kg][j] + slope * (float)(key - qr);
        s[kg][j] = (key <= qr) ? sv : -1e30f;
      }
    // ---- online softmax (row spread over 16 lanes) ----
    float al[4], rs[4];
#pragma unroll
    for (int j = 0; j < 4; j++) {
      float v = fmaxf(fmaxf(s[0][j], s[1][j]), fmaxf(s[2][j], s[3][j]));
      v = fmaxf(v, __shfl_xor(v, 1));
      v = fmaxf(v, __shfl_xor(v, 2));
      v = fmaxf(v, __shfl_xor(v, 4));
      v = fmaxf(v, __shfl_xor(v, 8));
      float nm = fmaxf(mrow[j], v);
      al[j] = __expf(mrow[j] - nm);
      mrow[j] = nm;
      rs[j] = 0.f;
    }
#pragma unroll
    for (int kg = 0; kg < 4; kg++)
#pragma unroll
      for (int j = 0; j < 4; j++) {
        float p = __expf(s[kg][j] - mrow[j]);
        s[kg][j] = p;
        rs[j] += p;
      }
#pragma unroll
    for (int j = 0; j < 4; j++) {
      rs[j] += __shfl_xor(rs[j], 1);
      rs[j] += __shfl_xor(rs[j], 2);
      rs[j] += __shfl_xor(rs[j], 4);
      rs[j] += __shfl_xor(rs[j], 8);
      lsum[j] = lsum[j] * al[j] + rs[j];
    }
#pragma unroll
    for (int dg = 0; dg < 4; dg++)
#pragma unroll
      for (int j = 0; j < 4; j++) acc_o[dg][j] *= al[j];

    // ---- P: C-layout -> A-layout via wave-private LDS (no barrier) ----
#pragma unroll
    for (int kg = 0; kg < 4; kg++)
#pragma unroll
      for (int j = 0; j < 4; j++)
        Pl[w][rr + j][kg * 16 + cc] = f2bf(s[kg][j]);
    bf16x8 pa0 = *(const bf16x8*)&Pl[w][cc][kg8];
    bf16x8 pa1 = *(const bf16x8*)&Pl[w][cc][32 + kg8];

    // ---- O += P V  (V^T fragments contiguous from global) ----
#pragma unroll
    for (int kf = 0; kf < 2; kf++) {
      bf16x8 pf = (kf == 0) ? pa0 : pa1;
#pragma unroll
      for (int dg = 0; dg < 4; dg++) {
        bf16x8 vf = *(const bf16x8*)&Vg[(long)(dg * 16 + cc) * 2048 + kbase + kf * 32 + kg8];
        acc_o[dg] = __builtin_amdgcn_mfma_f32_16x16x32_bf16(pf, vf, acc_o[dg], 0, 0, 0);
      }
    }
  }

  // ---- all waves done with Pl; reuse LDS for combine ----
  __syncthreads();
#pragma unroll
  for (int dg = 0; dg < 4; dg++)
#pragma unroll
    for (int j = 0; j < 4; j++)
      Ol[w][rr + j][dg * 16 + cc] = acc_o[dg][j];
  if (cc == 0) {
#pragma unroll
    for (int j = 0; j < 4; j++) {
      ml[w][0][rr + j] = mrow[j];
      ml[w][1][rr + j] = lsum[j];
    }
  }
  __syncthreads();

  // ---- combine 4 waves' partials; thread t -> (row r, dims d0..d0+3) ----
  const int r = t >> 4, d0 = (t & 15) * 4;
  float M = fmaxf(fmaxf(ml[0][0][r], ml[1][0][r]), fmaxf(ml[2][0][r], ml[3][0][r]));
  float L = 0.f;
  float o[4] = {0.f, 0.f, 0.f, 0.f};
#pragma unroll
  for (int ww = 0; ww < 4; ww++) {
    float sc = __expf(ml[ww][0][r] - M);
    L += sc * ml[ww][1][r];
#pragma unroll
    for (int i = 0; i < 4; i++) o[i] += sc * Ol[ww][r][d0 + i];
  }
  float inv = 1.f / L;
  ushort4 ov;
  ov.x = f2bf(o[0] * inv); ov.y = f2bf(o[1] * inv);
  ov.z = f2bf(o[2] * inv); ov.w = f2bf(o[3] * inv);
  *(ushort4*)&AT[((long)(b * 2048 + qrow0 + r)) * 1024 + h * 64 + d0] = ov;
}

// ---------------- launcher ----------------
extern "C" void kernel_launch(void* const* d_in, const int* in_sizes, int n_in,
                              void* d_out, int out_size, void* d_ws, size_t ws_size,
                              hipStream_t stream) {
  const float* x   = (const float*)d_in[0];
  const float* Wq  = (const float*)d_in[1];
  const float* Wkv = (const float*)d_in[2];
  const float* Wo  = (const float*)d_in[3];
  float* out = (float*)d_out;
  char* ws = (char*)d_ws;

  u16* xb    = (u16*)(ws);
  u16* wqkvb = (u16*)(ws + 8388608);
  u16* wob   = (u16*)(ws + 11534336);
  u16* Qb    = (u16*)(ws + 13631488);
  u16* Kb    = (u16*)(ws + 22020096);
  u16* VTb   = (u16*)(ws + 24117248);
  u16* AT    = (u16*)(ws + 26214400);

  cvt_kernel<<<6656, 256, 0, stream>>>(
      (const float4*)x, (const float4*)Wq, (const float4*)Wkv, (const float4*)Wo,
      (uint2*)xb, (uint2*)wqkvb, (uint2*)wob);

  gemm_qkv_kernel<<<dim3(32, 12), 256, 0, stream>>>(xb, wqkvb, Qb, Kb, VTb);

  attn_kernel<<<dim3(128, 16, 2), 256, 0, stream>>>(Qb, Kb, VTb, AT);

  gemm_out_kernel<<<dim3(32, 8), 256, 0, stream>>>(AT, wob, out);
}

// Round 3
// 237.091 us; speedup vs baseline: 1.7902x; 1.2372x over previous
//
#include <hip/hip_runtime.h>

typedef unsigned short u16;
typedef unsigned int u32;
typedef float f32x4 __attribute__((ext_vector_type(4)));
typedef float f32x16 __attribute__((ext_vector_type(16)));
typedef __bf16 bf16x8 __attribute__((ext_vector_type(8)));
typedef u32 u32x4 __attribute__((ext_vector_type(4)));

__device__ __forceinline__ u16 f2bf(float f) {
  u32 u = __builtin_bit_cast(u32, f);
  u32 r = (u + 0x7fffu + ((u >> 16) & 1u)) >> 16;
  return (u16)r;
}

__device__ __forceinline__ u32 pk2bf(float lo, float hi_) {
  u32 r;
  asm("v_cvt_pk_bf16_f32 %0, %1, %2" : "=v"(r) : "v"(lo), "v"(hi_));
  return r;
}

// v_permlane32_swap_b32: a[32:63] <-> b[0:31].
// After: a = {a.lo, b.lo}, b = {a.hi, b.hi}
__device__ __forceinline__ void plswap(u32 &a, u32 &b) {
#if __has_builtin(__builtin_amdgcn_permlane32_swap)
  auto r = __builtin_amdgcn_permlane32_swap(a, b, false, false);
  a = r[0]; b = r[1];
#else
  asm volatile("v_permlane32_swap_b32 %0, %1" : "+v"(a), "+v"(b));
#endif
}

__device__ __forceinline__ float xhalf_max(float x) {
  u32 a = __builtin_bit_cast(u32, x), b = a;
  plswap(a, b);
  return fmaxf(__builtin_bit_cast(float, a), __builtin_bit_cast(float, b));
}
__device__ __forceinline__ float xhalf_sum(float x) {
  u32 a = __builtin_bit_cast(u32, x), b = a;
  plswap(a, b);
  return __builtin_bit_cast(float, a) + __builtin_bit_cast(float, b);
}

// ---------------- fp32 -> bf16 conversion (x, Wq|Wkv concat, Wo) ----------------
__global__ __launch_bounds__(256) void cvt_kernel(
    const float4* __restrict__ x, const float4* __restrict__ wq,
    const float4* __restrict__ wkv, const float4* __restrict__ wo,
    uint2* __restrict__ xb, uint2* __restrict__ wqkvb, uint2* __restrict__ wob) {
  long i = (long)blockIdx.x * 256 + threadIdx.x;
  const float4* src; uint2* dst; long off;
  if (i < 1048576)      { src = x;   dst = xb;             off = i; }
  else if (i < 1310720) { src = wq;  dst = wqkvb;          off = i - 1048576; }
  else if (i < 1441792) { src = wkv; dst = wqkvb + 262144; off = i - 1310720; }
  else                  { src = wo;  dst = wob;            off = i - 1441792; }
  float4 v = src[off];
  uint2 o;
  o.x = ((u32)f2bf(v.y) << 16) | (u32)f2bf(v.x);
  o.y = ((u32)f2bf(v.w) << 16) | (u32)f2bf(v.z);
  dst[off] = o;
}

// ---------------- shared 128x128 bf16 GEMM core (C = A * W^T) ----------------
__device__ __forceinline__ void gemm_core(
    const u16* __restrict__ A, const u16* __restrict__ W, int K,
    f32x4 acc[4][4], u16 As[128][40], u16 Ws[128][40]) {
  const int t = threadIdx.x;
  const int lane = t & 63;
  const int w = t >> 6;
  const int wm = (w >> 1) * 64, wn = (w & 1) * 64;
  const long bm = (long)blockIdx.x * 128, bn = (long)blockIdx.y * 128;
  const int sr = t >> 2;
  const int sc = (t & 3) * 8;
  const int cc = lane & 15;
  const int kg8 = (lane >> 4) * 8;

#pragma unroll
  for (int i = 0; i < 4; i++)
#pragma unroll
    for (int j = 0; j < 4; j++) acc[i][j] = f32x4{0.f, 0.f, 0.f, 0.f};

  for (int k0 = 0; k0 < K; k0 += 32) {
    *(uint4*)&As[sr][sc]      = *(const uint4*)&A[(bm + sr) * K + k0 + sc];
    *(uint4*)&As[sr + 64][sc] = *(const uint4*)&A[(bm + sr + 64) * K + k0 + sc];
    *(uint4*)&Ws[sr][sc]      = *(const uint4*)&W[(bn + sr) * K + k0 + sc];
    *(uint4*)&Ws[sr + 64][sc] = *(const uint4*)&W[(bn + sr + 64) * K + k0 + sc];
    __syncthreads();
    bf16x8 af[4], wf[4];
#pragma unroll
    for (int i = 0; i < 4; i++) af[i] = *(const bf16x8*)&As[wm + i * 16 + cc][kg8];
#pragma unroll
    for (int j = 0; j < 4; j++) wf[j] = *(const bf16x8*)&Ws[wn + j * 16 + cc][kg8];
#pragma unroll
    for (int i = 0; i < 4; i++)
#pragma unroll
      for (int j = 0; j < 4; j++)
        acc[i][j] = __builtin_amdgcn_mfma_f32_16x16x32_bf16(af[i], wf[j], acc[i][j], 0, 0, 0);
    __syncthreads();
  }
}

// ---------------- GEMM1: qkv projection + routing epilogue ----------------
// Q is pre-scaled by SCALE*log2e so attention works in exp2 domain.
__global__ __launch_bounds__(256) void gemm_qkv_kernel(
    const u16* __restrict__ A, const u16* __restrict__ W,
    u16* __restrict__ Qb, u16* __restrict__ Kb, u16* __restrict__ VTb) {
  __shared__ __align__(16) u16 As[128][40];
  __shared__ __align__(16) u16 Ws[128][40];
  f32x4 acc[4][4];
  gemm_core(A, W, 1024, acc, As, Ws);
  const int t = threadIdx.x, lane = t & 63, w = t >> 6;
  const int wm = (w >> 1) * 64, wn = (w & 1) * 64;
  const int bm = blockIdx.x * 128, bn = blockIdx.y * 128;
  const int rr = (lane >> 4) * 4, cc = lane & 15;
#pragma unroll
  for (int i = 0; i < 4; i++)
#pragma unroll
    for (int jf = 0; jf < 4; jf++)
#pragma unroll
      for (int j = 0; j < 4; j++) {
        int m = bm + wm + i * 16 + rr + j;
        int n = bn + wn + jf * 16 + cc;
        float v = acc[i][jf][j];
        if (n < 1024) {
          Qb[(long)m * 1024 + n] = f2bf(v * 0.18033688011112043f);  // 0.125*log2(e)
        } else {
          int c = n - 1024, g = c >> 7, rm = c & 127;
          int b = m >> 11, pos = m & 2047;
          long base = (long)(b * 4 + g);
          if (rm < 64) Kb[(base * 2048 + pos) * 64 + rm] = f2bf(v);
          else         VTb[(base * 64 + (rm - 64)) * 2048 + pos] = f2bf(v);
        }
      }
}

// ---------------- GEMM2: output projection, fp32 out ----------------
__global__ __launch_bounds__(256) void gemm_out_kernel(
    const u16* __restrict__ A, const u16* __restrict__ W, float* __restrict__ out) {
  __shared__ __align__(16) u16 As[128][40];
  __shared__ __align__(16) u16 Ws[128][40];
  f32x4 acc[4][4];
  gemm_core(A, W, 1024, acc, As, Ws);
  const int t = threadIdx.x, lane = t & 63, w = t >> 6;
  const int wm = (w >> 1) * 64, wn = (w & 1) * 64;
  const int bm = blockIdx.x * 128, bn = blockIdx.y * 128;
  const int rr = (lane >> 4) * 4, cc = lane & 15;
#pragma unroll
  for (int i = 0; i < 4; i++)
#pragma unroll
    for (int jf = 0; jf < 4; jf++)
#pragma unroll
      for (int j = 0; j < 4; j++) {
        int m = bm + wm + i * 16 + rr + j;
        int n = bn + wn + jf * 16 + cc;
        out[(long)m * 1024 + n] = acc[i][jf][j];
      }
}

// ---------------- flash attention (causal + ALiBi, GQA) ----------------
// Swapped-operand 32x32x16 structure (m214-style, in-register softmax):
//  - QK^T: mfma(A=K, B=Q) -> S^T; lane owns q-row (lane&31), 16 keys in regs
//  - softmax: in-register tree + 1 permlane32_swap (no ds shuffles, no LDS)
//  - P->B-frag: 8 cvt_pk + 4 permlane32_swap per 32-key tile
//  - PV: mfma(A=V^T, B=P) -> O^T; rescale factor lane-uniform
// grid: (qtile32 0..63, head 0..15, batch 0..1); 4 waves key-split + combine.
__global__ __launch_bounds__(256, 4) void attn_kernel(
    const u16* __restrict__ Q, const u16* __restrict__ Kb,
    const u16* __restrict__ VTb, u16* __restrict__ AT) {
  __shared__ __align__(16) float Ol[4][32][68];
  __shared__ float ml[4][2][32];

  const int t = threadIdx.x, lane = t & 63, w = t >> 6;
  const int qt = 63 - (int)blockIdx.x;   // LPT: longest blocks first
  const int h = blockIdx.y, b = blockIdx.z;
  const int g = h >> 2;
  const int lam = lane & 31, hi = lane >> 5;
  const int qrow0 = qt * 32;
  const int kblocks = (qrow0 + 95) >> 6;

  // Q as B-operand frags: lane holds Q[qrow0+lam][dt*16 + hi*8 + j]
  const u16* Qrow = Q + ((long)(b * 2048 + qrow0 + lam)) * 1024 + h * 64 + hi * 8;
  bf16x8 qf0 = *(const bf16x8*)(Qrow);
  bf16x8 qf1 = *(const bf16x8*)(Qrow + 16);
  bf16x8 qf2 = *(const bf16x8*)(Qrow + 32);
  bf16x8 qf3 = *(const bf16x8*)(Qrow + 48);

  const u16* Kg = Kb  + ((long)(b * 4 + g)) * 2048 * 64;
  const u16* Vg = VTb + ((long)(b * 4 + g)) * 64 * 2048;

  f32x16 zv;
#pragma unroll
  for (int i = 0; i < 16; i++) zv[i] = 0.f;
  f32x16 acc0 = zv, acc1 = zv;   // O^T: acc[dt][r] = O[qrow0+lam][dt*32 + crow(r,hi)]
  float m = -1e30f, lsum = 0.f;

  const float slope2 = exp2f(-0.5f * (float)(h + 1)) * 1.44269504f;  // slope*log2(e)
  const float fqr = (float)(qrow0 + lam);

  // S^T tile for 32 keys at koff: C[key][qrow], key = koff + (r&3)+8*(r>>2)+4*hi
  auto qk_tile = [&](int koff) -> f32x16 {
    const u16* Ka = Kg + (long)(koff + lam) * 64 + hi * 8;
    bf16x8 k0 = *(const bf16x8*)(Ka);
    bf16x8 k1 = *(const bf16x8*)(Ka + 16);
    bf16x8 k2 = *(const bf16x8*)(Ka + 32);
    bf16x8 k3 = *(const bf16x8*)(Ka + 48);
    f32x16 s = zv;
    s = __builtin_amdgcn_mfma_f32_32x32x16_bf16(k0, qf0, s, 0, 0, 0);
    s = __builtin_amdgcn_mfma_f32_32x32x16_bf16(k1, qf1, s, 0, 0, 0);
    s = __builtin_amdgcn_mfma_f32_32x32x16_bf16(k2, qf2, s, 0, 0, 0);
    s = __builtin_amdgcn_mfma_f32_32x32x16_bf16(k3, qf3, s, 0, 0, 0);
    float kb0 = (float)(koff + 4 * hi) - fqr;   // key - qr base
    if (koff + 31 > qrow0) {                    // wave-uniform: tile needs mask
#pragma unroll
      for (int r = 0; r < 16; r++) {
        float d = kb0 + (float)((r & 3) + 8 * (r >> 2));
        s[r] = (d > 0.f) ? -1e30f : s[r] + slope2 * d;
      }
    } else {
#pragma unroll
      for (int r = 0; r < 16; r++)
        s[r] += slope2 * (kb0 + (float)((r & 3) + 8 * (r >> 2)));
    }
    return s;
  };

  // P (32 keys x 32 qrows, probs in s) -> B-frags -> O^T += V^T * P
  auto pv_tile = [&](const f32x16 &p, int koff) {
    u32 wd[8];
#pragma unroll
    for (int i = 0; i < 8; i++) wd[i] = pk2bf(p[2 * i], p[2 * i + 1]);
    plswap(wd[0], wd[2]); plswap(wd[1], wd[3]);
    plswap(wd[4], wd[6]); plswap(wd[5], wd[7]);
    bf16x8 pf0 = __builtin_bit_cast(bf16x8, u32x4{wd[0], wd[1], wd[2], wd[3]});
    bf16x8 pf1 = __builtin_bit_cast(bf16x8, u32x4{wd[4], wd[5], wd[6], wd[7]});
    const u16* Va = Vg + (long)lam * 2048 + koff + hi * 8;
    bf16x8 v00 = *(const bf16x8*)(Va);
    bf16x8 v01 = *(const bf16x8*)(Va + 16);
    bf16x8 v10 = *(const bf16x8*)(Va + 32 * 2048);
    bf16x8 v11 = *(const bf16x8*)(Va + 32 * 2048 + 16);
    acc0 = __builtin_amdgcn_mfma_f32_32x32x16_bf16(v00, pf0, acc0, 0, 0, 0);
    acc0 = __builtin_amdgcn_mfma_f32_32x32x16_bf16(v01, pf1, acc0, 0, 0, 0);
    acc1 = __builtin_amdgcn_mfma_f32_32x32x16_bf16(v10, pf0, acc1, 0, 0, 0);
    acc1 = __builtin_amdgcn_mfma_f32_32x32x16_bf16(v11, pf1, acc1, 0, 0, 0);
  };

  for (int jb = w; jb < kblocks; jb += 4) {
    const int kbase = jb * 64;
    f32x16 st0 = qk_tile(kbase);
    f32x16 st1;
    const bool t1v = (kbase + 32 <= qrow0 + 31);
    if (t1v) {
      st1 = qk_tile(kbase + 32);
    } else {
#pragma unroll
      for (int r = 0; r < 16; r++) st1[r] = -1e30f;
    }

    // ---- online softmax, fully in-register ----
    float red[8];
#pragma unroll
    for (int i = 0; i < 8; i++)
      red[i] = fmaxf(fmaxf(st0[i], st0[i + 8]), fmaxf(st1[i], st1[i + 8]));
#pragma unroll
    for (int i = 0; i < 4; i++) red[i] = fmaxf(red[i], red[i + 4]);
    float pm = fmaxf(fmaxf(red[0], red[1]), fmaxf(red[2], red[3]));
    pm = xhalf_max(pm);
    float mnew = fmaxf(m, pm);
    float al = exp2f(m - mnew);
    m = mnew;
    lsum *= al;
    acc0 *= al;
    acc1 *= al;
#pragma unroll
    for (int r = 0; r < 16; r++) st0[r] = exp2f(st0[r] - m);
#pragma unroll
    for (int r = 0; r < 16; r++) st1[r] = exp2f(st1[r] - m);
    {
      float sr[8];
#pragma unroll
      for (int i = 0; i < 8; i++) sr[i] = (st0[i] + st0[i + 8]) + (st1[i] + st1[i + 8]);
#pragma unroll
      for (int i = 0; i < 4; i++) sr[i] += sr[i + 4];
      float rs = (sr[0] + sr[1]) + (sr[2] + sr[3]);
      lsum += xhalf_sum(rs);
    }

    pv_tile(st0, kbase);
    if (t1v) pv_tile(st1, kbase + 32);
  }

  // ---- cross-wave combine ----
#pragma unroll
  for (int rq = 0; rq < 4; rq++) {
    *(f32x4*)&Ol[w][lam][8 * rq + 4 * hi] =
        f32x4{acc0[4 * rq], acc0[4 * rq + 1], acc0[4 * rq + 2], acc0[4 * rq + 3]};
    *(f32x4*)&Ol[w][lam][32 + 8 * rq + 4 * hi] =
        f32x4{acc1[4 * rq], acc1[4 * rq + 1], acc1[4 * rq + 2], acc1[4 * rq + 3]};
  }
  if (hi == 0) { ml[w][0][lam] = m; ml[w][1][lam] = lsum; }
  __syncthreads();

  const int r = t >> 3, c0 = (t & 7) * 8;
  float M = fmaxf(fmaxf(ml[0][0][r], ml[1][0][r]), fmaxf(ml[2][0][r], ml[3][0][r]));
  float o[8];
#pragma unroll
  for (int i = 0; i < 8; i++) o[i] = 0.f;
  float L = 0.f;
#pragma unroll
  for (int ww = 0; ww < 4; ww++) {
    float sc = exp2f(ml[ww][0][r] - M);
    L += sc * ml[ww][1][r];
#pragma unroll
    for (int i = 0; i < 8; i++) o[i] += sc * Ol[ww][r][c0 + i];
  }
  float inv = 1.f / L;
  uint4 ov;
  ov.x = ((u32)f2bf(o[1] * inv) << 16) | f2bf(o[0] * inv);
  ov.y = ((u32)f2bf(o[3] * inv) << 16) | f2bf(o[2] * inv);
  ov.z = ((u32)f2bf(o[5] * inv) << 16) | f2bf(o[4] * inv);
  ov.w = ((u32)f2bf(o[7] * inv) << 16) | f2bf(o[6] * inv);
  *(uint4*)&AT[((long)(b * 2048 + qrow0 + r)) * 1024 + h * 64 + c0] = ov;
}

// ---------------- launcher ----------------
extern "C" void kernel_launch(void* const* d_in, const int* in_sizes, int n_in,
                              void* d_out, int out_size, void* d_ws, size_t ws_size,
                              hipStream_t stream) {
  const float* x   = (const float*)d_in[0];
  const float* Wq  = (const float*)d_in[1];
  const float* Wkv = (const float*)d_in[2];
  const float* Wo  = (const float*)d_in[3];
  float* out = (float*)d_out;
  char* ws = (char*)d_ws;

  u16* xb    = (u16*)(ws);
  u16* wqkvb = (u16*)(ws + 8388608);
  u16* wob   = (u16*)(ws + 11534336);
  u16* Qb    = (u16*)(ws + 13631488);
  u16* Kb    = (u16*)(ws + 22020096);
  u16* VTb   = (u16*)(ws + 24117248);
  u16* AT    = (u16*)(ws + 26214400);

  cvt_kernel<<<6656, 256, 0, stream>>>(
      (const float4*)x, (const float4*)Wq, (const float4*)Wkv, (const float4*)Wo,
      (uint2*)xb, (uint2*)wqkvb, (uint2*)wob);

  gemm_qkv_kernel<<<dim3(32, 12), 256, 0, stream>>>(xb, wqkvb, Qb, Kb, VTb);

  attn_kernel<<<dim3(64, 16, 2), 256, 0, stream>>>(Qb, Kb, VTb, AT);

  gemm_out_kernel<<<dim3(32, 8), 256, 0, stream>>>(AT, wob, out);
}